// Round 8
// baseline (128.232 us; speedup 1.0000x reference)
//
#include <hip/hip_runtime.h>
#include <hip/hip_bf16.h>

// ---------------- problem constants ----------------
constexpr int Bn   = 4096;
constexpr int Nn   = 32;
constexpr int OBSn = 128;
constexpr int Hn   = 64;
constexpr int An   = 16;

// output offsets (floats)
constexpr size_t VOFF = (size_t)Bn * Nn * An;
constexpr size_t HOFF = VOFF + (size_t)Bn * Nn;
constexpr size_t COFF = HOFF + (size_t)Bn * Nn * Hn;

// global packed-weight tile bases (tile = 64 lanes x 16B = 1KB), prep output
constexpr int T_ENC  = 0;    // 16 tiles (ct*4+kt), K=128 N=64
constexpr int T_MSG0 = 16;   // 8 (unused)
constexpr int T_MSG1 = 24;   // 8
constexpr int T_WX0  = 32;   // 32 tiles (gate*8 + nt*2+p), gate order i,f,g,o
constexpr int T_WH0  = 64;   // 32 (unused)
constexpr int T_WX1  = 96;   // 32
constexpr int T_WH1  = 128;  // 32
constexpr int T_ACT  = 160;  // 2
constexpr int T_TOT  = 162;

// LDS staged tile bases (114 tiles = 114 KB)
constexpr int L_ENC  = 0;    // 16
constexpr int L_MSG1 = 16;   // 8
constexpr int L_WX0  = 24;   // 24: gates {i,g,o} at {+0,+8,+16}
constexpr int L_WX1  = 48;   // 32 (i,f,g,o at +0,+8,+16,+24)
constexpr int L_WH1  = 80;   // 32
constexpr int L_ACT  = 112;  // 2
constexpr int L_TOT  = 114;

typedef short bf16x8 __attribute__((ext_vector_type(8)));
typedef float f32x4  __attribute__((ext_vector_type(4)));

union FragU { uint u[4]; uint4 q; bf16x8 v; };

__device__ __forceinline__ uint pkbf(float a, float b) {
    __hip_bfloat16 ha = __float2bfloat16(a);
    __hip_bfloat16 hb = __float2bfloat16(b);
    unsigned short ua, ub;
    __builtin_memcpy(&ua, &ha, 2);
    __builtin_memcpy(&ub, &hb, 2);
    return (uint)ua | ((uint)ub << 16);
}

__device__ __forceinline__ float rcp_(float x) {
#if __has_builtin(__builtin_amdgcn_rcpf)
    return __builtin_amdgcn_rcpf(x);
#else
    return 1.0f / x;
#endif
}
__device__ __forceinline__ float exp2_(float x) {
#if __has_builtin(__builtin_amdgcn_exp2f)
    return __builtin_amdgcn_exp2f(x);
#else
    return exp2f(x);
#endif
}
__device__ __forceinline__ float fsig(float x)  { return rcp_(1.0f + exp2_(-1.44269504f * x)); }
__device__ __forceinline__ float ftanh(float x) { return 1.0f - 2.0f * rcp_(1.0f + exp2_(2.88539008f * x)); }

__device__ __forceinline__ f32x4 vsig(f32x4 x) {
    f32x4 r;
    #pragma unroll
    for (int i = 0; i < 4; ++i) r[i] = fsig(x[i]);
    return r;
}
__device__ __forceinline__ f32x4 vtanh(f32x4 x) {
    f32x4 r;
    #pragma unroll
    for (int i = 0; i < 4; ++i) r[i] = ftanh(x[i]);
    return r;
}

// ---------------- prep: pack weights to bf16 fragment-linear (unchanged) ----------------
__global__ void commnet_prep(
    const float* __restrict__ encW, const float* __restrict__ m0,
    const float* __restrict__ m1,   const float* __restrict__ wx0,
    const float* __restrict__ wh0,  const float* __restrict__ wx1,
    const float* __restrict__ wh1,  const float* __restrict__ aw,
    uint4* __restrict__ ws)
{
    int gid = blockIdx.x * 256 + threadIdx.x;
    if (gid >= T_TOT * 64) return;
    int tile = gid >> 6, lane = gid & 63;

    const float* W; int N, nt, kt, lt;
    if      (tile < T_MSG0) { W = encW; N = 64;  lt = tile;        nt = lt >> 2; kt = lt & 3; }
    else if (tile < T_MSG1) { W = m0;   N = 64;  lt = tile - T_MSG0; nt = lt >> 1; kt = lt & 1; }
    else if (tile < T_WX0 ) { W = m1;   N = 64;  lt = tile - T_MSG1; nt = lt >> 1; kt = lt & 1; }
    else if (tile < T_WH0 ) { W = wx0;  N = 256; lt = tile - T_WX0;  nt = lt >> 1; kt = lt & 1; }
    else if (tile < T_WX1 ) { W = wh0;  N = 256; lt = tile - T_WH0;  nt = lt >> 1; kt = lt & 1; }
    else if (tile < T_WH1 ) { W = wx1;  N = 256; lt = tile - T_WX1;  nt = lt >> 1; kt = lt & 1; }
    else if (tile < T_ACT ) { W = wh1;  N = 256; lt = tile - T_WH1;  nt = lt >> 1; kt = lt & 1; }
    else                    { W = aw;   N = 16;  lt = tile - T_ACT;  nt = 0;       kt = lt;     }

    int col = nt * 16 + (lane & 15);
    int kb  = kt * 32 + (lane >> 4) * 4;
    uint4 d;
    {
        int k0 = kb;
        d.x = pkbf(W[(k0 + 0) * N + col], W[(k0 + 1) * N + col]);
        d.y = pkbf(W[(k0 + 2) * N + col], W[(k0 + 3) * N + col]);
        k0 = kb + 16;
        d.z = pkbf(W[(k0 + 0) * N + col], W[(k0 + 1) * N + col]);
        d.w = pkbf(W[(k0 + 2) * N + col], W[(k0 + 3) * N + col]);
    }
    ws[(size_t)tile * 64 + lane] = d;
}

// ---------------- helpers ----------------
// Half-batch state layout: v[ct] is f32x4, component r is
//   state[batch_row = r0 + (lane&15)][channel = ct*16 + (lane>>4)*4 + r]
// == MFMA C/D layout of mfma(Wtile, stateFrag); after bf16 packing it is the
// B-operand fragment layout of the next matmul. Weights act as A-operands.
__device__ __forceinline__ void packState(const f32x4 v[4], FragU f[2]) {
    #pragma unroll
    for (int p = 0; p < 2; ++p) {
        f[p].u[0] = pkbf(v[2*p    ][0], v[2*p    ][1]);
        f[p].u[1] = pkbf(v[2*p    ][2], v[2*p    ][3]);
        f[p].u[2] = pkbf(v[2*p + 1][0], v[2*p + 1][1]);
        f[p].u[3] = pkbf(v[2*p + 1][2], v[2*p + 1][3]);
    }
}

// Recover z (bf16-rounded) from its packed fragments — saves 16 VGPRs of zv[].
__device__ __forceinline__ f32x4 unpackZ(const FragU f[2], int nt) {
    const uint a0 = f[nt >> 1].u[(nt & 1) * 2 + 0];
    const uint a1 = f[nt >> 1].u[(nt & 1) * 2 + 1];
    f32x4 r;
    r[0] = __uint_as_float(a0 << 16);
    r[1] = __uint_as_float(a0 & 0xffff0000u);
    r[2] = __uint_as_float(a1 << 16);
    r[3] = __uint_as_float(a1 & 0xffff0000u);
    return r;
}

// ---------------- main: PERSISTENT 256 blocks (1/CU) x 16 waves; 2 iterations ----------------
// Each wave owns 16 rows (half a batch); wave pair = 1 batch. ~120 unified
// regs/wave -> 16 waves/CU is the register ceiling (rounds 4-7 evidence), so
// the win here is removing dead windows, not adding waves: weights stage ONCE
// per CU (not once per shift), no inter-shift drain, and iteration-2 obs loads
// overlap other waves' iteration-1 tails.
__global__ __launch_bounds__(1024) void commnet_main(
    const float* __restrict__ obs, const uint4* __restrict__ wsQ,
    const float* __restrict__ enc_b,
    const float* __restrict__ msg_b0, const float* __restrict__ msg_b1,
    const float* __restrict__ lstm_b0, const float* __restrict__ lstm_b1,
    const float* __restrict__ act_b,
    const float* __restrict__ val_W, const float* __restrict__ val_b,
    float* __restrict__ out)
{
    __shared__ __align__(16) uint4 s_w[L_TOT * 64];   // 114 KB packed weights
    __shared__ __align__(16) float s_ex[16 * 64];     // 4 KB comm exchange

    const int t = threadIdx.x;
    const int wid = t >> 6, lane = t & 63;
    const int m = lane & 15, g4 = (lane >> 4) * 4;
    const int r0 = (wid & 1) * 16;

    // ---- stage weights global -> LDS (ONCE per block/CU), coalesced uint4 ----
    for (int i = t; i < L_TOT * 64; i += 1024) {
        const int lt = i >> 6, ln = i & 63;
        int src;
        if      (lt < L_MSG1) src = T_ENC  + lt;                  // ENC 16
        else if (lt < L_WX0)  src = T_MSG1 + (lt - L_MSG1);       // MSG1 8
        else if (lt < L_WX1) {                                    // WX0 gates i,g,o
            const int j = lt - L_WX0, s = j >> 3;
            const int gate = (s == 0) ? 0 : (s == 1) ? 2 : 3;
            src = T_WX0 + gate * 8 + (j & 7);
        }
        else                  src = T_WX1 + (lt - L_WX1);         // WX1|WH1|ACT contiguous
        s_w[i] = wsQ[(size_t)src * 64 + ln];
    }
    __syncthreads();

    #pragma unroll 1
    for (int it = 0; it < 2; ++it) {
        const int b = blockIdx.x * 16 + it * 8 + (wid >> 1);

        // ---- obs rows -> bf16 fragments ----
        FragU bo[4];
        {
            const float* ob = obs + ((size_t)b * Nn + r0 + m) * OBSn;
            #pragma unroll
            for (int kt = 0; kt < 4; ++kt) {
                const f32x4 p0 = *(const f32x4*)&ob[kt * 32 + g4];
                const f32x4 p1 = *(const f32x4*)&ob[kt * 32 + 16 + g4];
                bo[kt].u[0] = pkbf(p0[0], p0[1]);
                bo[kt].u[1] = pkbf(p0[2], p0[3]);
                bo[kt].u[2] = pkbf(p1[0], p1[1]);
                bo[kt].u[3] = pkbf(p1[2], p1[3]);
            }
        }

        f32x4 xv[4], cv[4], hv[4];
        FragU az[2], ah[2];

        // ---- encoder: x^T = tanh(enc_W^T @ obs^T + b) ----
        #pragma unroll
        for (int ct = 0; ct < 4; ++ct) {
            f32x4 a = {0.f, 0.f, 0.f, 0.f};
            #pragma unroll
            for (int kt = 0; kt < 4; ++kt) {
                FragU w; w.q = s_w[(L_ENC + ct * 4 + kt) * 64 + lane];
                a = __builtin_amdgcn_mfma_f32_16x16x32_bf16(w.v, bo[kt].v, a, 0, 0, 0);
            }
            xv[ct] = vtanh(a + *(const f32x4*)&enc_b[ct * 16 + g4]);
        }

        // ================= hop 0 (h=c=0: msg=bias, no f-gate, no Wh) =================
        {
            f32x4 zt[4];
            #pragma unroll
            for (int ct = 0; ct < 4; ++ct)
                zt[ct] = xv[ct] + *(const f32x4*)&msg_b0[ct * 16 + g4];
            packState(zt, az);       // z0 lives only as bf16 fragments
        }
        #pragma unroll
        for (int nt = 0; nt < 4; ++nt) {
            f32x4 ai = {0.f,0.f,0.f,0.f}, ag = {0.f,0.f,0.f,0.f}, ao = {0.f,0.f,0.f,0.f};
            #pragma unroll
            for (int p = 0; p < 2; ++p) {
                FragU w;
                w.q = s_w[(L_WX0 +  0 + nt * 2 + p) * 64 + lane];
                ai = __builtin_amdgcn_mfma_f32_16x16x32_bf16(w.v, az[p].v, ai, 0, 0, 0);
                w.q = s_w[(L_WX0 +  8 + nt * 2 + p) * 64 + lane];
                ag = __builtin_amdgcn_mfma_f32_16x16x32_bf16(w.v, az[p].v, ag, 0, 0, 0);
                w.q = s_w[(L_WX0 + 16 + nt * 2 + p) * 64 + lane];
                ao = __builtin_amdgcn_mfma_f32_16x16x32_bf16(w.v, az[p].v, ao, 0, 0, 0);
            }
            const f32x4 i_ = vsig (ai + *(const f32x4*)&lstm_b0[0 * 64 + nt * 16 + g4]);
            const f32x4 g_ = vtanh(ag + *(const f32x4*)&lstm_b0[2 * 64 + nt * 16 + g4]);
            const f32x4 o_ = vsig (ao + *(const f32x4*)&lstm_b0[3 * 64 + nt * 16 + g4]);
            cv[nt] = i_ * g_;
            hv[nt] = vtanh(o_ * vtanh(cv[nt]) + unpackZ(az, nt));
        }

        // ======= comm: S32 via shfl + partner-wave exchange (write/barrier/read) =======
        {
            f32x4 ps[4];
            #pragma unroll
            for (int ct = 0; ct < 4; ++ct) {
                f32x4 p = hv[ct];
                #pragma unroll
                for (int r = 0; r < 4; ++r) {
                    float s = p[r];
                    s += __shfl_xor(s, 1);
                    s += __shfl_xor(s, 2);
                    s += __shfl_xor(s, 4);
                    s += __shfl_xor(s, 8);
                    p[r] = s;
                }
                ps[ct] = p;          // sum over this wave's 16 rows (bcast to all m)
            }
            __syncthreads();         // s_ex safe: prior iteration's readers are done
            if (m == 0) {
                #pragma unroll
                for (int ct = 0; ct < 4; ++ct)
                    *(f32x4*)&s_ex[wid * 64 + ct * 16 + g4] = ps[ct];
            }
            __syncthreads();
            f32x4 cm[4];
            #pragma unroll
            for (int ct = 0; ct < 4; ++ct) {
                const f32x4 po = *(const f32x4*)&s_ex[(wid ^ 1) * 64 + ct * 16 + g4];
                cm[ct] = (ps[ct] + po - hv[ct]) * (1.0f / 31.0f);
            }
            packState(cm, az);       // az := comm fragments
        }

        // ---- msg = msg_W1^T @ comm^T + b ; z1 = x + msg ----
        {
            f32x4 zt[4];
            #pragma unroll
            for (int ct = 0; ct < 4; ++ct) {
                f32x4 a = {0.f, 0.f, 0.f, 0.f};
                #pragma unroll
                for (int p = 0; p < 2; ++p) {
                    FragU w; w.q = s_w[(L_MSG1 + ct * 2 + p) * 64 + lane];
                    a = __builtin_amdgcn_mfma_f32_16x16x32_bf16(w.v, az[p].v, a, 0, 0, 0);
                }
                zt[ct] = xv[ct] + a + *(const f32x4*)&msg_b1[ct * 16 + g4];
            }
            packState(zt, az);       // az := z1 fragments
            packState(hv, ah);       // ah := h fragments
        }

        // ================= hop 1 (full LSTM, fused per-nt) =================
        #pragma unroll
        for (int nt = 0; nt < 4; ++nt) {
            f32x4 ai = {0.f,0.f,0.f,0.f}, af = {0.f,0.f,0.f,0.f};
            f32x4 ag = {0.f,0.f,0.f,0.f}, ao = {0.f,0.f,0.f,0.f};
            #pragma unroll
            for (int p = 0; p < 2; ++p) {
                FragU w;
                w.q = s_w[(L_WX1 +  0 + nt * 2 + p) * 64 + lane];
                ai = __builtin_amdgcn_mfma_f32_16x16x32_bf16(w.v, az[p].v, ai, 0, 0, 0);
                w.q = s_w[(L_WH1 +  0 + nt * 2 + p) * 64 + lane];
                ai = __builtin_amdgcn_mfma_f32_16x16x32_bf16(w.v, ah[p].v, ai, 0, 0, 0);
                w.q = s_w[(L_WX1 +  8 + nt * 2 + p) * 64 + lane];
                af = __builtin_amdgcn_mfma_f32_16x16x32_bf16(w.v, az[p].v, af, 0, 0, 0);
                w.q = s_w[(L_WH1 +  8 + nt * 2 + p) * 64 + lane];
                af = __builtin_amdgcn_mfma_f32_16x16x32_bf16(w.v, ah[p].v, af, 0, 0, 0);
                w.q = s_w[(L_WX1 + 16 + nt * 2 + p) * 64 + lane];
                ag = __builtin_amdgcn_mfma_f32_16x16x32_bf16(w.v, az[p].v, ag, 0, 0, 0);
                w.q = s_w[(L_WH1 + 16 + nt * 2 + p) * 64 + lane];
                ag = __builtin_amdgcn_mfma_f32_16x16x32_bf16(w.v, ah[p].v, ag, 0, 0, 0);
                w.q = s_w[(L_WX1 + 24 + nt * 2 + p) * 64 + lane];
                ao = __builtin_amdgcn_mfma_f32_16x16x32_bf16(w.v, az[p].v, ao, 0, 0, 0);
                w.q = s_w[(L_WH1 + 24 + nt * 2 + p) * 64 + lane];
                ao = __builtin_amdgcn_mfma_f32_16x16x32_bf16(w.v, ah[p].v, ao, 0, 0, 0);
            }
            const f32x4 f_ = vsig (af + *(const f32x4*)&lstm_b1[1 * 64 + nt * 16 + g4]);
            const f32x4 i_ = vsig (ai + *(const f32x4*)&lstm_b1[0 * 64 + nt * 16 + g4]);
            const f32x4 g_ = vtanh(ag + *(const f32x4*)&lstm_b1[2 * 64 + nt * 16 + g4]);
            const f32x4 o_ = vsig (ao + *(const f32x4*)&lstm_b1[3 * 64 + nt * 16 + g4]);
            cv[nt] = f_ * cv[nt] + i_ * g_;
            hv[nt] = vtanh(o_ * vtanh(cv[nt]) + unpackZ(az, nt));
        }

        // ================= heads =================
        packState(hv, ah);           // final h fragments
        {
            f32x4 acc = {0.f, 0.f, 0.f, 0.f};
            #pragma unroll
            for (int p = 0; p < 2; ++p) {
                FragU w; w.q = s_w[(L_ACT + p) * 64 + lane];
                acc = __builtin_amdgcn_mfma_f32_16x16x32_bf16(w.v, ah[p].v, acc, 0, 0, 0);
            }
            *(f32x4*)&out[((size_t)b * Nn + r0 + m) * An + g4] =
                acc + *(const f32x4*)&act_b[g4];
        }
        // values
        {
            float pp = 0.f;
            #pragma unroll
            for (int ct = 0; ct < 4; ++ct) {
                const f32x4 vw = *(const f32x4*)&val_W[ct * 16 + g4];
                #pragma unroll
                for (int r = 0; r < 4; ++r)
                    pp = fmaf(hv[ct][r], vw[r], pp);
            }
            pp += __shfl_xor(pp, 16);
            pp += __shfl_xor(pp, 32);
            if (lane < 16)
                out[VOFF + (size_t)b * Nn + r0 + m] = pp + val_b[0];
        }
        // h_round, c_round — float4 per lane
        {
            float* oh = out + HOFF;
            float* oc = out + COFF;
            #pragma unroll
            for (int ct = 0; ct < 4; ++ct) {
                const size_t base = ((size_t)b * Nn + r0 + m) * Hn + ct * 16 + g4;
                *(f32x4*)&oh[base] = hv[ct];
                *(f32x4*)&oc[base] = cv[ct];
            }
        }
    }
}

// ---------------- launch ----------------
extern "C" void kernel_launch(void* const* d_in, const int* in_sizes, int n_in,
                              void* d_out, int out_size, void* d_ws, size_t ws_size,
                              hipStream_t stream) {
    const float* obs      = (const float*)d_in[0];
    const float* enc_W    = (const float*)d_in[1];
    const float* enc_b    = (const float*)d_in[2];
    const float* msg_W0   = (const float*)d_in[3];
    const float* msg_b0   = (const float*)d_in[4];
    const float* msg_W1   = (const float*)d_in[5];
    const float* msg_b1   = (const float*)d_in[6];
    const float* lstm_Wx0 = (const float*)d_in[7];
    const float* lstm_Wh0 = (const float*)d_in[8];
    const float* lstm_b0  = (const float*)d_in[9];
    const float* lstm_Wx1 = (const float*)d_in[10];
    const float* lstm_Wh1 = (const float*)d_in[11];
    const float* lstm_b1  = (const float*)d_in[12];
    const float* act_W    = (const float*)d_in[13];
    const float* act_b    = (const float*)d_in[14];
    const float* val_W    = (const float*)d_in[15];
    const float* val_b    = (const float*)d_in[16];

    uint4* ws = (uint4*)d_ws;

    commnet_prep<<<(T_TOT * 64 + 255) / 256, 256, 0, stream>>>(
        enc_W, msg_W0, msg_W1, lstm_Wx0, lstm_Wh0, lstm_Wx1, lstm_Wh1, act_W, ws);

    commnet_main<<<Bn / 16, 1024, 0, stream>>>(
        obs, ws, enc_b, msg_b0, msg_b1, lstm_b0, lstm_b1,
        act_b, val_W, val_b, (float*)d_out);
}

// Round 9
// 70.980 us; speedup vs baseline: 1.8066x; 1.8066x over previous
//
#include <hip/hip_runtime.h>
#include <hip/hip_bf16.h>

// ---------------- problem constants ----------------
constexpr int Bn   = 4096;
constexpr int Nn   = 32;
constexpr int OBSn = 128;
constexpr int Hn   = 64;
constexpr int An   = 16;

// output offsets (floats)
constexpr size_t VOFF = (size_t)Bn * Nn * An;
constexpr size_t HOFF = VOFF + (size_t)Bn * Nn;
constexpr size_t COFF = HOFF + (size_t)Bn * Nn * Hn;

// global packed-weight tile bases (tile = 64 lanes x 16B = 1KB), prep output
constexpr int T_ENC  = 0;    // 16 tiles (ct*4+kt), K=128 N=64
constexpr int T_MSG0 = 16;   // 8 (unused)
constexpr int T_MSG1 = 24;   // 8
constexpr int T_WX0  = 32;   // 32 tiles (gate*8 + nt*2+p), gate order i,f,g,o
constexpr int T_WH0  = 64;   // 32 (unused)
constexpr int T_WX1  = 96;   // 32
constexpr int T_WH1  = 128;  // 32
constexpr int T_ACT  = 160;  // 2
constexpr int T_TOT  = 162;

// LDS staged tile bases (114 tiles = 114 KB)
constexpr int L_ENC  = 0;    // 16
constexpr int L_MSG1 = 16;   // 8
constexpr int L_WX0  = 24;   // 24: gates {i,g,o} at {+0,+8,+16}
constexpr int L_WX1  = 48;   // 32 (i,f,g,o at +0,+8,+16,+24)
constexpr int L_WH1  = 80;   // 32
constexpr int L_ACT  = 112;  // 2
constexpr int L_TOT  = 114;

typedef short bf16x8 __attribute__((ext_vector_type(8)));
typedef float f32x4  __attribute__((ext_vector_type(4)));

union FragU { uint u[4]; uint4 q; bf16x8 v; };

__device__ __forceinline__ uint pkbf(float a, float b) {
    __hip_bfloat16 ha = __float2bfloat16(a);
    __hip_bfloat16 hb = __float2bfloat16(b);
    unsigned short ua, ub;
    __builtin_memcpy(&ua, &ha, 2);
    __builtin_memcpy(&ub, &hb, 2);
    return (uint)ua | ((uint)ub << 16);
}

__device__ __forceinline__ float rcp_(float x) {
#if __has_builtin(__builtin_amdgcn_rcpf)
    return __builtin_amdgcn_rcpf(x);
#else
    return 1.0f / x;
#endif
}
__device__ __forceinline__ float exp2_(float x) {
#if __has_builtin(__builtin_amdgcn_exp2f)
    return __builtin_amdgcn_exp2f(x);
#else
    return exp2f(x);
#endif
}
__device__ __forceinline__ float fsig(float x)  { return rcp_(1.0f + exp2_(-1.44269504f * x)); }
__device__ __forceinline__ float ftanh(float x) { return 1.0f - 2.0f * rcp_(1.0f + exp2_(2.88539008f * x)); }

__device__ __forceinline__ f32x4 vsig(f32x4 x) {
    f32x4 r;
    #pragma unroll
    for (int i = 0; i < 4; ++i) r[i] = fsig(x[i]);
    return r;
}
__device__ __forceinline__ f32x4 vtanh(f32x4 x) {
    f32x4 r;
    #pragma unroll
    for (int i = 0; i < 4; ++i) r[i] = ftanh(x[i]);
    return r;
}

// ---------------- prep: pack weights to bf16 fragment-linear (unchanged) ----------------
__global__ void commnet_prep(
    const float* __restrict__ encW, const float* __restrict__ m0,
    const float* __restrict__ m1,   const float* __restrict__ wx0,
    const float* __restrict__ wh0,  const float* __restrict__ wx1,
    const float* __restrict__ wh1,  const float* __restrict__ aw,
    uint4* __restrict__ ws)
{
    int gid = blockIdx.x * 256 + threadIdx.x;
    if (gid >= T_TOT * 64) return;
    int tile = gid >> 6, lane = gid & 63;

    const float* W; int N, nt, kt, lt;
    if      (tile < T_MSG0) { W = encW; N = 64;  lt = tile;        nt = lt >> 2; kt = lt & 3; }
    else if (tile < T_MSG1) { W = m0;   N = 64;  lt = tile - T_MSG0; nt = lt >> 1; kt = lt & 1; }
    else if (tile < T_WX0 ) { W = m1;   N = 64;  lt = tile - T_MSG1; nt = lt >> 1; kt = lt & 1; }
    else if (tile < T_WH0 ) { W = wx0;  N = 256; lt = tile - T_WX0;  nt = lt >> 1; kt = lt & 1; }
    else if (tile < T_WX1 ) { W = wh0;  N = 256; lt = tile - T_WH0;  nt = lt >> 1; kt = lt & 1; }
    else if (tile < T_WH1 ) { W = wx1;  N = 256; lt = tile - T_WX1;  nt = lt >> 1; kt = lt & 1; }
    else if (tile < T_ACT ) { W = wh1;  N = 256; lt = tile - T_WH1;  nt = lt >> 1; kt = lt & 1; }
    else                    { W = aw;   N = 16;  lt = tile - T_ACT;  nt = 0;       kt = lt;     }

    int col = nt * 16 + (lane & 15);
    int kb  = kt * 32 + (lane >> 4) * 4;
    uint4 d;
    {
        int k0 = kb;
        d.x = pkbf(W[(k0 + 0) * N + col], W[(k0 + 1) * N + col]);
        d.y = pkbf(W[(k0 + 2) * N + col], W[(k0 + 3) * N + col]);
        k0 = kb + 16;
        d.z = pkbf(W[(k0 + 0) * N + col], W[(k0 + 1) * N + col]);
        d.w = pkbf(W[(k0 + 2) * N + col], W[(k0 + 3) * N + col]);
    }
    ws[(size_t)tile * 64 + lane] = d;
}

// ---------------- helpers ----------------
// Half-batch state layout: v[ct] is f32x4, component r is
//   state[batch_row = r0 + (lane&15)][channel = ct*16 + (lane>>4)*4 + r]
__device__ __forceinline__ void packState(const f32x4 v[4], FragU f[2]) {
    #pragma unroll
    for (int p = 0; p < 2; ++p) {
        f[p].u[0] = pkbf(v[2*p    ][0], v[2*p    ][1]);
        f[p].u[1] = pkbf(v[2*p    ][2], v[2*p    ][3]);
        f[p].u[2] = pkbf(v[2*p + 1][0], v[2*p + 1][1]);
        f[p].u[3] = pkbf(v[2*p + 1][2], v[2*p + 1][3]);
    }
}

__device__ __forceinline__ f32x4 unpackZ(const FragU f[2], int nt) {
    const uint a0 = f[nt >> 1].u[(nt & 1) * 2 + 0];
    const uint a1 = f[nt >> 1].u[(nt & 1) * 2 + 1];
    f32x4 r;
    r[0] = __uint_as_float(a0 << 16);
    r[1] = __uint_as_float(a0 & 0xffff0000u);
    r[2] = __uint_as_float(a1 << 16);
    r[3] = __uint_as_float(a1 & 0xffff0000u);
    return r;
}

// ---------------- main: round-7 structure + PHASE-SPLIT layers ----------------
// 1 block = 16 waves = 8 batches (wave pair = 1 batch, 16 rows each). Grid 512.
// Phase-split: issue ALL gate MFMAs (12-16 independent accumulators -> AGPRs,
// deep lgkm/MFMA pipelining) THEN all activations (16 independent trans chains).
// Round-7's serialized per-nt groups left every wave stalled ~60% of the time.
// NO persistent loop (round-8: loop -> 64-reg split + 300MB spill).
__global__ __launch_bounds__(1024) void commnet_main(
    const float* __restrict__ obs, const uint4* __restrict__ wsQ,
    const float* __restrict__ enc_b,
    const float* __restrict__ msg_b0, const float* __restrict__ msg_b1,
    const float* __restrict__ lstm_b0, const float* __restrict__ lstm_b1,
    const float* __restrict__ act_b,
    const float* __restrict__ val_W, const float* __restrict__ val_b,
    float* __restrict__ out)
{
    __shared__ __align__(16) uint4 s_w[L_TOT * 64];   // 114 KB packed weights
    __shared__ __align__(16) float s_ex[16 * 64];     // 4 KB comm exchange

    const int t = threadIdx.x;
    const int wid = t >> 6, lane = t & 63;
    const int m = lane & 15, g4 = (lane >> 4) * 4;
    const int b  = blockIdx.x * 8 + (wid >> 1);
    const int r0 = (wid & 1) * 16;

    // ---- obs rows -> bf16 fragments (issued before staging barrier) ----
    FragU bo[4];
    {
        const float* ob = obs + ((size_t)b * Nn + r0 + m) * OBSn;
        #pragma unroll
        for (int kt = 0; kt < 4; ++kt) {
            const f32x4 p0 = *(const f32x4*)&ob[kt * 32 + g4];
            const f32x4 p1 = *(const f32x4*)&ob[kt * 32 + 16 + g4];
            bo[kt].u[0] = pkbf(p0[0], p0[1]);
            bo[kt].u[1] = pkbf(p0[2], p0[3]);
            bo[kt].u[2] = pkbf(p1[0], p1[1]);
            bo[kt].u[3] = pkbf(p1[2], p1[3]);
        }
    }

    // ---- stage weights global -> LDS, coalesced uint4 ----
    for (int i = t; i < L_TOT * 64; i += 1024) {
        const int lt = i >> 6, ln = i & 63;
        int src;
        if      (lt < L_MSG1) src = T_ENC  + lt;
        else if (lt < L_WX0)  src = T_MSG1 + (lt - L_MSG1);
        else if (lt < L_WX1) {
            const int j = lt - L_WX0, s = j >> 3;
            const int gate = (s == 0) ? 0 : (s == 1) ? 2 : 3;
            src = T_WX0 + gate * 8 + (j & 7);
        }
        else                  src = T_WX1 + (lt - L_WX1);
        s_w[i] = wsQ[(size_t)src * 64 + ln];
    }
    __syncthreads();

    f32x4 xv[4], cv[4], hv[4];
    FragU az[2], ah[2];

    // ---- encoder: MFMA phase then activation phase ----
    {
        f32x4 ax[4];
        #pragma unroll
        for (int ct = 0; ct < 4; ++ct) ax[ct] = (f32x4){0.f, 0.f, 0.f, 0.f};
        #pragma unroll
        for (int ct = 0; ct < 4; ++ct)
            #pragma unroll
            for (int kt = 0; kt < 4; ++kt) {
                FragU w; w.q = s_w[(L_ENC + ct * 4 + kt) * 64 + lane];
                ax[ct] = __builtin_amdgcn_mfma_f32_16x16x32_bf16(w.v, bo[kt].v, ax[ct], 0, 0, 0);
            }
        #pragma unroll
        for (int ct = 0; ct < 4; ++ct)
            xv[ct] = vtanh(ax[ct] + *(const f32x4*)&enc_b[ct * 16 + g4]);
    }

    // ================= hop 0 (h=c=0: msg=bias, no f-gate, no Wh) =================
    {
        f32x4 zt[4];
        #pragma unroll
        for (int ct = 0; ct < 4; ++ct)
            zt[ct] = xv[ct] + *(const f32x4*)&msg_b0[ct * 16 + g4];
        packState(zt, az);           // z0 lives only as bf16 fragments
    }
    {
        f32x4 ai[4], ag[4], ao[4];
        #pragma unroll
        for (int nt = 0; nt < 4; ++nt) {
            ai[nt] = (f32x4){0.f, 0.f, 0.f, 0.f};
            ag[nt] = (f32x4){0.f, 0.f, 0.f, 0.f};
            ao[nt] = (f32x4){0.f, 0.f, 0.f, 0.f};
        }
        // MFMA phase: 24 MFMAs, 12 independent accumulators
        #pragma unroll
        for (int nt = 0; nt < 4; ++nt)
            #pragma unroll
            for (int p = 0; p < 2; ++p) {
                FragU w;
                w.q = s_w[(L_WX0 +  0 + nt * 2 + p) * 64 + lane];
                ai[nt] = __builtin_amdgcn_mfma_f32_16x16x32_bf16(w.v, az[p].v, ai[nt], 0, 0, 0);
                w.q = s_w[(L_WX0 +  8 + nt * 2 + p) * 64 + lane];
                ag[nt] = __builtin_amdgcn_mfma_f32_16x16x32_bf16(w.v, az[p].v, ag[nt], 0, 0, 0);
                w.q = s_w[(L_WX0 + 16 + nt * 2 + p) * 64 + lane];
                ao[nt] = __builtin_amdgcn_mfma_f32_16x16x32_bf16(w.v, az[p].v, ao[nt], 0, 0, 0);
            }
        // activation phase: 4 independent chains
        #pragma unroll
        for (int nt = 0; nt < 4; ++nt) {
            const f32x4 i_ = vsig (ai[nt] + *(const f32x4*)&lstm_b0[0 * 64 + nt * 16 + g4]);
            const f32x4 g_ = vtanh(ag[nt] + *(const f32x4*)&lstm_b0[2 * 64 + nt * 16 + g4]);
            const f32x4 o_ = vsig (ao[nt] + *(const f32x4*)&lstm_b0[3 * 64 + nt * 16 + g4]);
            cv[nt] = i_ * g_;
            hv[nt] = vtanh(o_ * vtanh(cv[nt]) + unpackZ(az, nt));
        }
    }

    // ======= comm: S32 via shfl + partner-wave exchange =======
    {
        f32x4 ps[4];
        #pragma unroll
        for (int ct = 0; ct < 4; ++ct) {
            f32x4 p = hv[ct];
            #pragma unroll
            for (int r = 0; r < 4; ++r) {
                float s = p[r];
                s += __shfl_xor(s, 1);
                s += __shfl_xor(s, 2);
                s += __shfl_xor(s, 4);
                s += __shfl_xor(s, 8);
                p[r] = s;
            }
            ps[ct] = p;              // sum over this wave's 16 rows
        }
        if (m == 0) {
            #pragma unroll
            for (int ct = 0; ct < 4; ++ct)
                *(f32x4*)&s_ex[wid * 64 + ct * 16 + g4] = ps[ct];
        }
        __syncthreads();
        f32x4 cm[4];
        #pragma unroll
        for (int ct = 0; ct < 4; ++ct) {
            const f32x4 po = *(const f32x4*)&s_ex[(wid ^ 1) * 64 + ct * 16 + g4];
            cm[ct] = (ps[ct] + po - hv[ct]) * (1.0f / 31.0f);
        }
        packState(cm, az);           // az := comm fragments
    }

    // ---- msg = msg_W1^T @ comm^T + b ; z1 = x + msg (MFMA phase then add) ----
    {
        f32x4 am[4];
        #pragma unroll
        for (int ct = 0; ct < 4; ++ct) am[ct] = (f32x4){0.f, 0.f, 0.f, 0.f};
        #pragma unroll
        for (int ct = 0; ct < 4; ++ct)
            #pragma unroll
            for (int p = 0; p < 2; ++p) {
                FragU w; w.q = s_w[(L_MSG1 + ct * 2 + p) * 64 + lane];
                am[ct] = __builtin_amdgcn_mfma_f32_16x16x32_bf16(w.v, az[p].v, am[ct], 0, 0, 0);
            }
        f32x4 zt[4];
        #pragma unroll
        for (int ct = 0; ct < 4; ++ct)
            zt[ct] = xv[ct] + am[ct] + *(const f32x4*)&msg_b1[ct * 16 + g4];
        packState(zt, az);           // az := z1 fragments
        packState(hv, ah);           // ah := h fragments
    }

    // ================= hop 1: 64 MFMAs into 16 accumulators, then activations =================
    {
        f32x4 ai[4], af[4], ag[4], ao[4];
        #pragma unroll
        for (int nt = 0; nt < 4; ++nt) {
            ai[nt] = (f32x4){0.f, 0.f, 0.f, 0.f};
            af[nt] = (f32x4){0.f, 0.f, 0.f, 0.f};
            ag[nt] = (f32x4){0.f, 0.f, 0.f, 0.f};
            ao[nt] = (f32x4){0.f, 0.f, 0.f, 0.f};
        }
        #pragma unroll
        for (int nt = 0; nt < 4; ++nt)
            #pragma unroll
            for (int p = 0; p < 2; ++p) {
                FragU w;
                w.q = s_w[(L_WX1 +  0 + nt * 2 + p) * 64 + lane];
                ai[nt] = __builtin_amdgcn_mfma_f32_16x16x32_bf16(w.v, az[p].v, ai[nt], 0, 0, 0);
                w.q = s_w[(L_WH1 +  0 + nt * 2 + p) * 64 + lane];
                ai[nt] = __builtin_amdgcn_mfma_f32_16x16x32_bf16(w.v, ah[p].v, ai[nt], 0, 0, 0);
                w.q = s_w[(L_WX1 +  8 + nt * 2 + p) * 64 + lane];
                af[nt] = __builtin_amdgcn_mfma_f32_16x16x32_bf16(w.v, az[p].v, af[nt], 0, 0, 0);
                w.q = s_w[(L_WH1 +  8 + nt * 2 + p) * 64 + lane];
                af[nt] = __builtin_amdgcn_mfma_f32_16x16x32_bf16(w.v, ah[p].v, af[nt], 0, 0, 0);
                w.q = s_w[(L_WX1 + 16 + nt * 2 + p) * 64 + lane];
                ag[nt] = __builtin_amdgcn_mfma_f32_16x16x32_bf16(w.v, az[p].v, ag[nt], 0, 0, 0);
                w.q = s_w[(L_WH1 + 16 + nt * 2 + p) * 64 + lane];
                ag[nt] = __builtin_amdgcn_mfma_f32_16x16x32_bf16(w.v, ah[p].v, ag[nt], 0, 0, 0);
                w.q = s_w[(L_WX1 + 24 + nt * 2 + p) * 64 + lane];
                ao[nt] = __builtin_amdgcn_mfma_f32_16x16x32_bf16(w.v, az[p].v, ao[nt], 0, 0, 0);
                w.q = s_w[(L_WH1 + 24 + nt * 2 + p) * 64 + lane];
                ao[nt] = __builtin_amdgcn_mfma_f32_16x16x32_bf16(w.v, ah[p].v, ao[nt], 0, 0, 0);
            }
        #pragma unroll
        for (int nt = 0; nt < 4; ++nt) {
            const f32x4 f_ = vsig (af[nt] + *(const f32x4*)&lstm_b1[1 * 64 + nt * 16 + g4]);
            const f32x4 i_ = vsig (ai[nt] + *(const f32x4*)&lstm_b1[0 * 64 + nt * 16 + g4]);
            const f32x4 g_ = vtanh(ag[nt] + *(const f32x4*)&lstm_b1[2 * 64 + nt * 16 + g4]);
            const f32x4 o_ = vsig (ao[nt] + *(const f32x4*)&lstm_b1[3 * 64 + nt * 16 + g4]);
            cv[nt] = f_ * cv[nt] + i_ * g_;
            hv[nt] = vtanh(o_ * vtanh(cv[nt]) + unpackZ(az, nt));
        }
    }

    // ================= heads =================
    packState(hv, ah);               // final h fragments
    {
        f32x4 acc = {0.f, 0.f, 0.f, 0.f};
        #pragma unroll
        for (int p = 0; p < 2; ++p) {
            FragU w; w.q = s_w[(L_ACT + p) * 64 + lane];
            acc = __builtin_amdgcn_mfma_f32_16x16x32_bf16(w.v, ah[p].v, acc, 0, 0, 0);
        }
        *(f32x4*)&out[((size_t)b * Nn + r0 + m) * An + g4] =
            acc + *(const f32x4*)&act_b[g4];
    }
    // values
    {
        float pp = 0.f;
        #pragma unroll
        for (int ct = 0; ct < 4; ++ct) {
            const f32x4 vw = *(const f32x4*)&val_W[ct * 16 + g4];
            #pragma unroll
            for (int r = 0; r < 4; ++r)
                pp = fmaf(hv[ct][r], vw[r], pp);
        }
        pp += __shfl_xor(pp, 16);
        pp += __shfl_xor(pp, 32);
        if (lane < 16)
            out[VOFF + (size_t)b * Nn + r0 + m] = pp + val_b[0];
    }
    // h_round, c_round — float4 per lane
    {
        float* oh = out + HOFF;
        float* oc = out + COFF;
        #pragma unroll
        for (int ct = 0; ct < 4; ++ct) {
            const size_t base = ((size_t)b * Nn + r0 + m) * Hn + ct * 16 + g4;
            *(f32x4*)&oh[base] = hv[ct];
            *(f32x4*)&oc[base] = cv[ct];
        }
    }
}

// ---------------- launch ----------------
extern "C" void kernel_launch(void* const* d_in, const int* in_sizes, int n_in,
                              void* d_out, int out_size, void* d_ws, size_t ws_size,
                              hipStream_t stream) {
    const float* obs      = (const float*)d_in[0];
    const float* enc_W    = (const float*)d_in[1];
    const float* enc_b    = (const float*)d_in[2];
    const float* msg_W0   = (const float*)d_in[3];
    const float* msg_b0   = (const float*)d_in[4];
    const float* msg_W1   = (const float*)d_in[5];
    const float* msg_b1   = (const float*)d_in[6];
    const float* lstm_Wx0 = (const float*)d_in[7];
    const float* lstm_Wh0 = (const float*)d_in[8];
    const float* lstm_b0  = (const float*)d_in[9];
    const float* lstm_Wx1 = (const float*)d_in[10];
    const float* lstm_Wh1 = (const float*)d_in[11];
    const float* lstm_b1  = (const float*)d_in[12];
    const float* act_W    = (const float*)d_in[13];
    const float* act_b    = (const float*)d_in[14];
    const float* val_W    = (const float*)d_in[15];
    const float* val_b    = (const float*)d_in[16];

    uint4* ws = (uint4*)d_ws;

    commnet_prep<<<(T_TOT * 64 + 255) / 256, 256, 0, stream>>>(
        enc_W, msg_W0, msg_W1, lstm_Wx0, lstm_Wh0, lstm_Wx1, lstm_Wh1, act_W, ws);

    commnet_main<<<Bn / 8, 1024, 0, stream>>>(
        obs, ws, enc_b, msg_b0, msg_b1, lstm_b0, lstm_b1,
        act_b, val_W, val_b, (float*)d_out);
}

// Round 10
// 64.141 us; speedup vs baseline: 1.9992x; 1.1066x over previous
//
#include <hip/hip_runtime.h>
#include <hip/hip_bf16.h>

// ---------------- problem constants ----------------
constexpr int Bn   = 4096;
constexpr int Nn   = 32;
constexpr int OBSn = 128;
constexpr int Hn   = 64;
constexpr int An   = 16;

// output offsets (floats)
constexpr size_t VOFF = (size_t)Bn * Nn * An;
constexpr size_t HOFF = VOFF + (size_t)Bn * Nn;
constexpr size_t COFF = HOFF + (size_t)Bn * Nn * Hn;

// global packed-weight tile bases (tile = 64 lanes x 16B = 1KB), prep output
constexpr int T_ENC  = 0;    // 16 tiles (ct*4+kt), K=128 N=64
constexpr int T_MSG0 = 16;   // 8 (unused)
constexpr int T_MSG1 = 24;   // 8
constexpr int T_WX0  = 32;   // 32 tiles (gate*8 + nt*2+p), gate order i,f,g,o
constexpr int T_WH0  = 64;   // 32 (unused)
constexpr int T_WX1  = 96;   // 32
constexpr int T_WH1  = 128;  // 32
constexpr int T_ACT  = 160;  // 2
constexpr int T_TOT  = 162;

// LDS staged tile bases (114 tiles = 114 KB)
constexpr int L_ENC  = 0;    // 16
constexpr int L_MSG1 = 16;   // 8
constexpr int L_WX0  = 24;   // 24: gates {i,g,o} at {+0,+8,+16}
constexpr int L_WX1  = 48;   // 32 (i,f,g,o at +0,+8,+16,+24)
constexpr int L_WH1  = 80;   // 32
constexpr int L_ACT  = 112;  // 2
constexpr int L_TOT  = 114;

typedef short bf16x8 __attribute__((ext_vector_type(8)));
typedef float f32x4  __attribute__((ext_vector_type(4)));

union FragU { uint u[4]; uint4 q; bf16x8 v; };

__device__ __forceinline__ uint pkbf(float a, float b) {
    __hip_bfloat16 ha = __float2bfloat16(a);
    __hip_bfloat16 hb = __float2bfloat16(b);
    unsigned short ua, ub;
    __builtin_memcpy(&ua, &ha, 2);
    __builtin_memcpy(&ub, &hb, 2);
    return (uint)ua | ((uint)ub << 16);
}

__device__ __forceinline__ float rcp_(float x) {
#if __has_builtin(__builtin_amdgcn_rcpf)
    return __builtin_amdgcn_rcpf(x);
#else
    return 1.0f / x;
#endif
}
__device__ __forceinline__ float exp2_(float x) {
#if __has_builtin(__builtin_amdgcn_exp2f)
    return __builtin_amdgcn_exp2f(x);
#else
    return exp2f(x);
#endif
}
__device__ __forceinline__ float fsig(float x)  { return rcp_(1.0f + exp2_(-1.44269504f * x)); }
__device__ __forceinline__ float ftanh(float x) { return 1.0f - 2.0f * rcp_(1.0f + exp2_(2.88539008f * x)); }

__device__ __forceinline__ f32x4 vsig(f32x4 x) {
    f32x4 r;
    #pragma unroll
    for (int i = 0; i < 4; ++i) r[i] = fsig(x[i]);
    return r;
}
__device__ __forceinline__ f32x4 vtanh(f32x4 x) {
    f32x4 r;
    #pragma unroll
    for (int i = 0; i < 4; ++i) r[i] = ftanh(x[i]);
    return r;
}

// ---------------- prep: pack weights to bf16 fragment-linear (unchanged) ----------------
__global__ void commnet_prep(
    const float* __restrict__ encW, const float* __restrict__ m0,
    const float* __restrict__ m1,   const float* __restrict__ wx0,
    const float* __restrict__ wh0,  const float* __restrict__ wx1,
    const float* __restrict__ wh1,  const float* __restrict__ aw,
    uint4* __restrict__ ws)
{
    int gid = blockIdx.x * 256 + threadIdx.x;
    if (gid >= T_TOT * 64) return;
    int tile = gid >> 6, lane = gid & 63;

    const float* W; int N, nt, kt, lt;
    if      (tile < T_MSG0) { W = encW; N = 64;  lt = tile;        nt = lt >> 2; kt = lt & 3; }
    else if (tile < T_MSG1) { W = m0;   N = 64;  lt = tile - T_MSG0; nt = lt >> 1; kt = lt & 1; }
    else if (tile < T_WX0 ) { W = m1;   N = 64;  lt = tile - T_MSG1; nt = lt >> 1; kt = lt & 1; }
    else if (tile < T_WH0 ) { W = wx0;  N = 256; lt = tile - T_WX0;  nt = lt >> 1; kt = lt & 1; }
    else if (tile < T_WX1 ) { W = wh0;  N = 256; lt = tile - T_WH0;  nt = lt >> 1; kt = lt & 1; }
    else if (tile < T_WH1 ) { W = wx1;  N = 256; lt = tile - T_WX1;  nt = lt >> 1; kt = lt & 1; }
    else if (tile < T_ACT ) { W = wh1;  N = 256; lt = tile - T_WH1;  nt = lt >> 1; kt = lt & 1; }
    else                    { W = aw;   N = 16;  lt = tile - T_ACT;  nt = 0;       kt = lt;     }

    int col = nt * 16 + (lane & 15);
    int kb  = kt * 32 + (lane >> 4) * 4;
    uint4 d;
    {
        int k0 = kb;
        d.x = pkbf(W[(k0 + 0) * N + col], W[(k0 + 1) * N + col]);
        d.y = pkbf(W[(k0 + 2) * N + col], W[(k0 + 3) * N + col]);
        k0 = kb + 16;
        d.z = pkbf(W[(k0 + 0) * N + col], W[(k0 + 1) * N + col]);
        d.w = pkbf(W[(k0 + 2) * N + col], W[(k0 + 3) * N + col]);
    }
    ws[(size_t)tile * 64 + lane] = d;
}

// ---------------- helpers ----------------
// Half-batch state layout: v[ct] is f32x4, component r is
//   state[batch_row = r0 + (lane&15)][channel = ct*16 + (lane>>4)*4 + r]
__device__ __forceinline__ void packState(const f32x4 v[4], FragU f[2]) {
    #pragma unroll
    for (int p = 0; p < 2; ++p) {
        f[p].u[0] = pkbf(v[2*p    ][0], v[2*p    ][1]);
        f[p].u[1] = pkbf(v[2*p    ][2], v[2*p    ][3]);
        f[p].u[2] = pkbf(v[2*p + 1][0], v[2*p + 1][1]);
        f[p].u[3] = pkbf(v[2*p + 1][2], v[2*p + 1][3]);
    }
}

__device__ __forceinline__ f32x4 unpackZ(const FragU f[2], int nt) {
    const uint a0 = f[nt >> 1].u[(nt & 1) * 2 + 0];
    const uint a1 = f[nt >> 1].u[(nt & 1) * 2 + 1];
    f32x4 r;
    r[0] = __uint_as_float(a0 << 16);
    r[1] = __uint_as_float(a0 & 0xffff0000u);
    r[2] = __uint_as_float(a1 << 16);
    r[3] = __uint_as_float(a1 & 0xffff0000u);
    return r;
}

// ---------------- main: round-7 structure + DE-LOCKSTEPPED waves ----------------
// 1 block = 16 waves = 8 batches (wave pair = 1 batch, 16 rows each). Grid 512.
// Round-7 counters showed serial phase execution (VALU 37% + LDS 18% + mem 27%
// summing to ~100% of dur): barriers kept all 16 waves in lockstep, so pipes
// never overlap across waves. This version removes the mid-kernel block barrier
// (pair-local LDS handshake instead) and skews pairs by ~256cyc steps after
// staging so waves on one SIMD occupy different chain phases.
__global__ __launch_bounds__(1024) void commnet_main(
    const float* __restrict__ obs, const uint4* __restrict__ wsQ,
    const float* __restrict__ enc_b,
    const float* __restrict__ msg_b0, const float* __restrict__ msg_b1,
    const float* __restrict__ lstm_b0, const float* __restrict__ lstm_b1,
    const float* __restrict__ act_b,
    const float* __restrict__ val_W, const float* __restrict__ val_b,
    float* __restrict__ out)
{
    __shared__ __align__(16) uint4 s_w[L_TOT * 64];   // 114 KB packed weights
    __shared__ __align__(16) float s_ex[16 * 64];     // 4 KB comm exchange
    __shared__ int s_flag[16];                        // pair handshake flags

    const int t = threadIdx.x;
    const int wid = t >> 6, lane = t & 63;
    const int m = lane & 15, g4 = (lane >> 4) * 4;
    const int b  = blockIdx.x * 8 + (wid >> 1);
    const int r0 = (wid & 1) * 16;

    // ---- obs rows -> bf16 fragments (issued before staging barrier) ----
    FragU bo[4];
    {
        const float* ob = obs + ((size_t)b * Nn + r0 + m) * OBSn;
        #pragma unroll
        for (int kt = 0; kt < 4; ++kt) {
            const f32x4 p0 = *(const f32x4*)&ob[kt * 32 + g4];
            const f32x4 p1 = *(const f32x4*)&ob[kt * 32 + 16 + g4];
            bo[kt].u[0] = pkbf(p0[0], p0[1]);
            bo[kt].u[1] = pkbf(p0[2], p0[3]);
            bo[kt].u[2] = pkbf(p1[0], p1[1]);
            bo[kt].u[3] = pkbf(p1[2], p1[3]);
        }
    }

    if (t < 16) s_flag[t] = 0;

    // ---- stage weights global -> LDS, coalesced uint4 ----
    for (int i = t; i < L_TOT * 64; i += 1024) {
        const int lt = i >> 6, ln = i & 63;
        int src;
        if      (lt < L_MSG1) src = T_ENC  + lt;
        else if (lt < L_WX0)  src = T_MSG1 + (lt - L_MSG1);
        else if (lt < L_WX1) {
            const int j = lt - L_WX0, s = j >> 3;
            const int gate = (s == 0) ? 0 : (s == 1) ? 2 : 3;
            src = T_WX0 + gate * 8 + (j & 7);
        }
        else                  src = T_WX1 + (lt - L_WX1);
        s_w[i] = wsQ[(size_t)src * 64 + ln];
    }
    __syncthreads();   // the ONLY block-wide barrier

    // ---- deliberate phase skew: pair p delays ~p*256 cyc so same-SIMD waves
    //      sit at different chain positions (phase mixing across waves) ----
    {
        const int pair = wid >> 1;
        for (int i = 0; i < pair; ++i) __builtin_amdgcn_s_sleep(4);
    }

    f32x4 xv[4], cv[4], hv[4];
    FragU az[2], ah[2];

    // ---- encoder: x^T = tanh(enc_W^T @ obs^T + b) ----
    #pragma unroll
    for (int ct = 0; ct < 4; ++ct) {
        f32x4 a = {0.f, 0.f, 0.f, 0.f};
        #pragma unroll
        for (int kt = 0; kt < 4; ++kt) {
            FragU w; w.q = s_w[(L_ENC + ct * 4 + kt) * 64 + lane];
            a = __builtin_amdgcn_mfma_f32_16x16x32_bf16(w.v, bo[kt].v, a, 0, 0, 0);
        }
        xv[ct] = vtanh(a + *(const f32x4*)&enc_b[ct * 16 + g4]);
    }

    // ================= hop 0 (h=c=0: msg=bias, no f-gate, no Wh) =================
    {
        f32x4 zt[4];
        #pragma unroll
        for (int ct = 0; ct < 4; ++ct)
            zt[ct] = xv[ct] + *(const f32x4*)&msg_b0[ct * 16 + g4];
        packState(zt, az);           // z0 lives only as bf16 fragments
    }
    #pragma unroll
    for (int nt = 0; nt < 4; ++nt) {
        f32x4 ai = {0.f,0.f,0.f,0.f}, ag = {0.f,0.f,0.f,0.f}, ao = {0.f,0.f,0.f,0.f};
        #pragma unroll
        for (int p = 0; p < 2; ++p) {
            FragU w;
            w.q = s_w[(L_WX0 +  0 + nt * 2 + p) * 64 + lane];
            ai = __builtin_amdgcn_mfma_f32_16x16x32_bf16(w.v, az[p].v, ai, 0, 0, 0);
            w.q = s_w[(L_WX0 +  8 + nt * 2 + p) * 64 + lane];
            ag = __builtin_amdgcn_mfma_f32_16x16x32_bf16(w.v, az[p].v, ag, 0, 0, 0);
            w.q = s_w[(L_WX0 + 16 + nt * 2 + p) * 64 + lane];
            ao = __builtin_amdgcn_mfma_f32_16x16x32_bf16(w.v, az[p].v, ao, 0, 0, 0);
        }
        const f32x4 i_ = vsig (ai + *(const f32x4*)&lstm_b0[0 * 64 + nt * 16 + g4]);
        const f32x4 g_ = vtanh(ag + *(const f32x4*)&lstm_b0[2 * 64 + nt * 16 + g4]);
        const f32x4 o_ = vsig (ao + *(const f32x4*)&lstm_b0[3 * 64 + nt * 16 + g4]);
        cv[nt] = i_ * g_;
        hv[nt] = vtanh(o_ * vtanh(cv[nt]) + unpackZ(az, nt));
    }

    // ======= comm: S32 via shfl + PAIR-LOCAL exchange (no block barrier) =======
    {
        f32x4 ps[4];
        #pragma unroll
        for (int ct = 0; ct < 4; ++ct) {
            f32x4 p = hv[ct];
            #pragma unroll
            for (int r = 0; r < 4; ++r) {
                float s = p[r];
                s += __shfl_xor(s, 1);
                s += __shfl_xor(s, 2);
                s += __shfl_xor(s, 4);
                s += __shfl_xor(s, 8);
                p[r] = s;
            }
            ps[ct] = p;              // sum over this wave's 16 rows
        }
        if (m == 0) {
            #pragma unroll
            for (int ct = 0; ct < 4; ++ct)
                *(f32x4*)&s_ex[wid * 64 + ct * 16 + g4] = ps[ct];
        }
        __threadfence_block();                       // data visible before flag
        if (lane == 0) ((volatile int*)s_flag)[wid] = 1;
        {
            volatile int* vf = (volatile int*)&s_flag[wid ^ 1];
            while (*vf == 0) { __builtin_amdgcn_s_sleep(1); }
        }
        __threadfence_block();                       // flag seen before data reads
        f32x4 cm[4];
        #pragma unroll
        for (int ct = 0; ct < 4; ++ct) {
            const f32x4 po = *(const f32x4*)&s_ex[(wid ^ 1) * 64 + ct * 16 + g4];
            cm[ct] = (ps[ct] + po - hv[ct]) * (1.0f / 31.0f);
        }
        packState(cm, az);           // az := comm fragments
    }

    // ---- msg = msg_W1^T @ comm^T + b ; z1 = x + msg ----
    {
        f32x4 zt[4];
        #pragma unroll
        for (int ct = 0; ct < 4; ++ct) {
            f32x4 a = {0.f, 0.f, 0.f, 0.f};
            #pragma unroll
            for (int p = 0; p < 2; ++p) {
                FragU w; w.q = s_w[(L_MSG1 + ct * 2 + p) * 64 + lane];
                a = __builtin_amdgcn_mfma_f32_16x16x32_bf16(w.v, az[p].v, a, 0, 0, 0);
            }
            zt[ct] = xv[ct] + a + *(const f32x4*)&msg_b1[ct * 16 + g4];
        }
        packState(zt, az);           // az := z1 fragments
        packState(hv, ah);           // ah := h fragments
    }

    // ================= hop 1 (full LSTM, fused per-nt) =================
    #pragma unroll
    for (int nt = 0; nt < 4; ++nt) {
        f32x4 ai = {0.f,0.f,0.f,0.f}, af = {0.f,0.f,0.f,0.f};
        f32x4 ag = {0.f,0.f,0.f,0.f}, ao = {0.f,0.f,0.f,0.f};
        #pragma unroll
        for (int p = 0; p < 2; ++p) {
            FragU w;
            w.q = s_w[(L_WX1 +  0 + nt * 2 + p) * 64 + lane];
            ai = __builtin_amdgcn_mfma_f32_16x16x32_bf16(w.v, az[p].v, ai, 0, 0, 0);
            w.q = s_w[(L_WH1 +  0 + nt * 2 + p) * 64 + lane];
            ai = __builtin_amdgcn_mfma_f32_16x16x32_bf16(w.v, ah[p].v, ai, 0, 0, 0);
            w.q = s_w[(L_WX1 +  8 + nt * 2 + p) * 64 + lane];
            af = __builtin_amdgcn_mfma_f32_16x16x32_bf16(w.v, az[p].v, af, 0, 0, 0);
            w.q = s_w[(L_WH1 +  8 + nt * 2 + p) * 64 + lane];
            af = __builtin_amdgcn_mfma_f32_16x16x32_bf16(w.v, ah[p].v, af, 0, 0, 0);
            w.q = s_w[(L_WX1 + 16 + nt * 2 + p) * 64 + lane];
            ag = __builtin_amdgcn_mfma_f32_16x16x32_bf16(w.v, az[p].v, ag, 0, 0, 0);
            w.q = s_w[(L_WH1 + 16 + nt * 2 + p) * 64 + lane];
            ag = __builtin_amdgcn_mfma_f32_16x16x32_bf16(w.v, ah[p].v, ag, 0, 0, 0);
            w.q = s_w[(L_WX1 + 24 + nt * 2 + p) * 64 + lane];
            ao = __builtin_amdgcn_mfma_f32_16x16x32_bf16(w.v, az[p].v, ao, 0, 0, 0);
            w.q = s_w[(L_WH1 + 24 + nt * 2 + p) * 64 + lane];
            ao = __builtin_amdgcn_mfma_f32_16x16x32_bf16(w.v, ah[p].v, ao, 0, 0, 0);
        }
        const f32x4 f_ = vsig (af + *(const f32x4*)&lstm_b1[1 * 64 + nt * 16 + g4]);
        const f32x4 i_ = vsig (ai + *(const f32x4*)&lstm_b1[0 * 64 + nt * 16 + g4]);
        const f32x4 g_ = vtanh(ag + *(const f32x4*)&lstm_b1[2 * 64 + nt * 16 + g4]);
        const f32x4 o_ = vsig (ao + *(const f32x4*)&lstm_b1[3 * 64 + nt * 16 + g4]);
        cv[nt] = f_ * cv[nt] + i_ * g_;
        hv[nt] = vtanh(o_ * vtanh(cv[nt]) + unpackZ(az, nt));
    }

    // ================= heads =================
    packState(hv, ah);               // final h fragments
    {
        f32x4 acc = {0.f, 0.f, 0.f, 0.f};
        #pragma unroll
        for (int p = 0; p < 2; ++p) {
            FragU w; w.q = s_w[(L_ACT + p) * 64 + lane];
            acc = __builtin_amdgcn_mfma_f32_16x16x32_bf16(w.v, ah[p].v, acc, 0, 0, 0);
        }
        *(f32x4*)&out[((size_t)b * Nn + r0 + m) * An + g4] =
            acc + *(const f32x4*)&act_b[g4];
    }
    // values
    {
        float pp = 0.f;
        #pragma unroll
        for (int ct = 0; ct < 4; ++ct) {
            const f32x4 vw = *(const f32x4*)&val_W[ct * 16 + g4];
            #pragma unroll
            for (int r = 0; r < 4; ++r)
                pp = fmaf(hv[ct][r], vw[r], pp);
        }
        pp += __shfl_xor(pp, 16);
        pp += __shfl_xor(pp, 32);
        if (lane < 16)
            out[VOFF + (size_t)b * Nn + r0 + m] = pp + val_b[0];
    }
    // h_round, c_round — float4 per lane
    {
        float* oh = out + HOFF;
        float* oc = out + COFF;
        #pragma unroll
        for (int ct = 0; ct < 4; ++ct) {
            const size_t base = ((size_t)b * Nn + r0 + m) * Hn + ct * 16 + g4;
            *(f32x4*)&oh[base] = hv[ct];
            *(f32x4*)&oc[base] = cv[ct];
        }
    }
}

// ---------------- launch ----------------
extern "C" void kernel_launch(void* const* d_in, const int* in_sizes, int n_in,
                              void* d_out, int out_size, void* d_ws, size_t ws_size,
                              hipStream_t stream) {
    const float* obs      = (const float*)d_in[0];
    const float* enc_W    = (const float*)d_in[1];
    const float* enc_b    = (const float*)d_in[2];
    const float* msg_W0   = (const float*)d_in[3];
    const float* msg_b0   = (const float*)d_in[4];
    const float* msg_W1   = (const float*)d_in[5];
    const float* msg_b1   = (const float*)d_in[6];
    const float* lstm_Wx0 = (const float*)d_in[7];
    const float* lstm_Wh0 = (const float*)d_in[8];
    const float* lstm_b0  = (const float*)d_in[9];
    const float* lstm_Wx1 = (const float*)d_in[10];
    const float* lstm_Wh1 = (const float*)d_in[11];
    const float* lstm_b1  = (const float*)d_in[12];
    const float* act_W    = (const float*)d_in[13];
    const float* act_b    = (const float*)d_in[14];
    const float* val_W    = (const float*)d_in[15];
    const float* val_b    = (const float*)d_in[16];

    uint4* ws = (uint4*)d_ws;

    commnet_prep<<<(T_TOT * 64 + 255) / 256, 256, 0, stream>>>(
        enc_W, msg_W0, msg_W1, lstm_Wx0, lstm_Wh0, lstm_Wx1, lstm_Wh1, act_W, ws);

    commnet_main<<<Bn / 8, 1024, 0, stream>>>(
        obs, ws, enc_b, msg_b0, msg_b1, lstm_b0, lstm_b1,
        act_b, val_W, val_b, (float*)d_out);
}